// Round 2
// baseline (1487.699 us; speedup 1.0000x reference)
//
#include <hip/hip_runtime.h>
#include <hip/hip_bf16.h>

typedef unsigned short u16;
typedef __attribute__((ext_vector_type(8))) short s16x8;   // 8 bf16 in 4 VGPRs (guide-verified idiom)
typedef __attribute__((ext_vector_type(4))) float f32x4;

#define GAS(p) ((const __attribute__((address_space(1))) void*)(p))
#define LAS(p) ((__attribute__((address_space(3))) void*)(p))

// ---------------- Pass 1: per-column partial min/max ----------------
__global__ void kminmax(const float* __restrict__ x, float* __restrict__ pmin,
                        float* __restrict__ pmax, int rpb) {
    const int c = threadIdx.x;                 // 0..511
    const size_t r0 = (size_t)blockIdx.x * rpb;
    float mn = 1e30f, mx = -1e30f;
    for (int i = 0; i < rpb; ++i) {
        float v = x[(r0 + i) * 512 + c];
        mn = fminf(mn, v);
        mx = fmaxf(mx, v);
    }
    pmin[blockIdx.x * 512 + c] = mn;
    pmax[blockIdx.x * 512 + c] = mx;
}

// ---------------- Pass 2: finalize min/range per column ----------------
__global__ void kbounds(const float* __restrict__ pmin, const float* __restrict__ pmax,
                        float* __restrict__ cmin, float* __restrict__ crange, int nparts) {
    const int c = threadIdx.x;
    float mn = 1e30f, mx = -1e30f;
    for (int p = 0; p < nparts; ++p) {
        mn = fminf(mn, pmin[p * 512 + c]);
        mx = fmaxf(mx, pmax[p * 512 + c]);
    }
    cmin[c] = mn;
    crange[c] = __fsub_rn(mx, mn);   // matches numpy (b_max - b_min) in fp32
}

// ---------------- Pass 3: discretize -> bf16 ----------------
// idx = #{k in 1..24 : fl(mn + fl(range*fl(k/25))) < v}   (searchsorted side='left')
// Fast path via u=(v-mn)*(25/range); exact fp32 boundary compare only when u is
// within 1e-3 of an integer (u-error bound ~6e-6, 150x margin).
__global__ void kdisc(const float* __restrict__ x, const float* __restrict__ cmin,
                      const float* __restrict__ crange, __hip_bfloat16* __restrict__ d,
                      int rpb) {
    const int c = threadIdx.x;                 // 0..511
    const float mn = cmin[c];
    const float rg = crange[c];
    const float s = __fdiv_rn(25.0f, rg);
    const size_t r0 = (size_t)blockIdx.x * rpb;
    for (int i = 0; i < rpb; ++i) {
        const size_t off = (r0 + i) * 512 + c;
        const float v = x[off];
        const float u = __fmul_rn(__fsub_rn(v, mn), s);
        const float rn = rintf(u);
        int idx;
        if (fabsf(u - rn) > 1e-3f) {
            idx = (int)ceilf(u) - 1;
        } else {
            int kc = (int)rn;
            kc = kc < 1 ? 1 : (kc > 24 ? 24 : kc);
            const float cf = __fdiv_rn((float)kc, 25.0f);     // == np.arange/25 in fp32
            const float b = __fadd_rn(mn, __fmul_rn(rg, cf)); // exact ref boundary
            idx = (int)rn - 1 + ((b < v) ? 1 : 0);
        }
        idx = idx < 0 ? 0 : (idx > 24 ? 24 : idx);
        d[off] = __float2bfloat16((float)idx);                // 0..24 exact in bf16
    }
}

// ---------------- Weight cast + transpose: W[K,N] fp32 -> Wt[N,K] bf16 ----------------
__global__ void ktc(const float* __restrict__ W, __hip_bfloat16* __restrict__ Wt, int N) {
    const int i = blockIdx.x * 256 + threadIdx.x;             // over N*512
    if (i >= N * 512) return;
    const int n = i >> 9;
    const int k = i & 511;
    Wt[i] = __float2bfloat16(W[(size_t)k * N + n]);
}

__global__ void kzero(float* __restrict__ p) {
    if (threadIdx.x == 0 && blockIdx.x == 0) p[0] = 0.0f;
}

// ---------------- Fused GEMM + bias + ReLU ----------------
// C = relu(A @ Wt^T + bias), A/Wt bf16, fp32 accumulate. 128x128 tile, 4 waves
// 2x2, each wave 4x4 mfma_f32_16x16x32_bf16, BK=32, global_load_lds width=16,
// XOR k-group swizzle (worst 2-way LDS conflict = free, m136).
// Dual A/C base pointers: blockIdx.y >= mtiles_half selects the second half
// (the two batch halves live in non-contiguous scratch slots).
template <int OUTF>
__global__ __launch_bounds__(256) void gemm_bias_relu(
    const u16* __restrict__ A0, const u16* __restrict__ A1,
    const u16* __restrict__ Bt, const float* __restrict__ bias,
    void* C0, void* C1, int N, int K, int mtiles_half) {
    __shared__ __attribute__((aligned(16))) u16 As[128 * 32];
    __shared__ __attribute__((aligned(16))) u16 Bs[128 * 32];

    const int t = threadIdx.x;
    const int lane = t & 63;
    const int wave = t >> 6;
    int bm = blockIdx.y;
    const u16* A = A0;
    void* Cout = C0;
    if (bm >= mtiles_half) { A = A1; Cout = C1; bm -= mtiles_half; }
    const int bn = blockIdx.x;
    const int wrow = (wave >> 1) * 64;
    const int wcol = (wave & 1) * 64;

    f32x4 acc[4][4] = {};

    // staging: thread t owns LDS 16B slot t*16 (srow = t>>2, slot-group = t&3);
    // it fetches global k-group (t&3) ^ ((srow>>1)&3). Same kg for srow and srow+64.
    const int srow = t >> 2;
    const int kg0 = (t & 3) ^ ((srow >> 1) & 3);

    const u16* a0 = A + (size_t)(bm * 128 + srow) * K + kg0 * 8;
    const u16* a1 = a0 + (size_t)64 * K;
    const u16* b0 = Bt + (size_t)(bn * 128 + srow) * K + kg0 * 8;
    const u16* b1 = b0 + (size_t)64 * K;

    char* asb = (char*)As;
    char* bsb = (char*)Bs;
    const int woff = wave * 1024;   // wave-uniform LDS dest base (+lane*16 implicit)

    const int kq = lane >> 4;
    const int lr = lane & 15;

    for (int k0 = 0; k0 < K; k0 += 32) {
        __syncthreads();
        __builtin_amdgcn_global_load_lds(GAS(a0 + k0), LAS(asb + woff), 16, 0, 0);
        __builtin_amdgcn_global_load_lds(GAS(a1 + k0), LAS(asb + 4096 + woff), 16, 0, 0);
        __builtin_amdgcn_global_load_lds(GAS(b0 + k0), LAS(bsb + woff), 16, 0, 0);
        __builtin_amdgcn_global_load_lds(GAS(b1 + k0), LAS(bsb + 4096 + woff), 16, 0, 0);
        __syncthreads();

        s16x8 af[4], bfr[4];
#pragma unroll
        for (int mt = 0; mt < 4; ++mt) {
            const int row = wrow + mt * 16 + lr;
            const int g = kq ^ ((row >> 1) & 3);
            af[mt] = *(const s16x8*)(asb + row * 64 + g * 16);
        }
#pragma unroll
        for (int nt = 0; nt < 4; ++nt) {
            const int row = wcol + nt * 16 + lr;
            const int g = kq ^ ((row >> 1) & 3);
            bfr[nt] = *(const s16x8*)(bsb + row * 64 + g * 16);
        }
#pragma unroll
        for (int mt = 0; mt < 4; ++mt)
#pragma unroll
            for (int nt = 0; nt < 4; ++nt)
                acc[mt][nt] = __builtin_amdgcn_mfma_f32_16x16x32_bf16(
                    af[mt], bfr[nt], acc[mt][nt], 0, 0, 0);
    }

    // Epilogue. C/D layout (m89-verified): col = lane&15, row = (lane>>4)*4 + reg.
    float bv[4];
#pragma unroll
    for (int nt = 0; nt < 4; ++nt) bv[nt] = bias[bn * 128 + wcol + nt * 16 + lr];

#pragma unroll
    for (int mt = 0; mt < 4; ++mt) {
#pragma unroll
        for (int nt = 0; nt < 4; ++nt) {
            const int col = bn * 128 + wcol + nt * 16 + lr;
#pragma unroll
            for (int r = 0; r < 4; ++r) {
                const int row = bm * 128 + wrow + mt * 16 + kq * 4 + r;
                const float v = fmaxf(acc[mt][nt][r] + bv[nt], 0.0f);
                if (OUTF)
                    ((float*)Cout)[(size_t)row * N + col] = v;
                else
                    ((__hip_bfloat16*)Cout)[(size_t)row * N + col] = __float2bfloat16(v);
            }
        }
    }
}

extern "C" void kernel_launch(void* const* d_in, const int* in_sizes, int n_in,
                              void* d_out, int out_size, void* d_ws, size_t ws_size,
                              hipStream_t stream) {
    float* xf          = (float*)d_in[0];      // mutated as scratch; harness restores
    const float* W_in  = (const float*)d_in[1];
    const float* b_in  = (const float*)d_in[2];
    const float* W_h   = (const float*)d_in[3];
    const float* b_h   = (const float*)d_in[4];
    const float* W_out = (const float*)d_in[5];
    const float* b_out = (const float*)d_in[6];
    float* out = (float*)d_out;

    const int B = in_sizes[0] / 512;           // 131072
    const int HB = B / 2;                      // 65536 rows per half
    const size_t SLOT = (size_t)HB * 512;      // bf16 elements per slot (64 MiB)
    const int K = 512;

    // Five 64-MiB bf16 slots: d_out + four carved from the (dead-after-read)
    // x input buffer. d_ws holds only ~2.2 MB of small stuff.
    __hip_bfloat16* x0lo  = (__hip_bfloat16*)xf;
    __hip_bfloat16* x0hi  = x0lo + SLOT;
    __hip_bfloat16* x1lo  = x0hi + SLOT;
    __hip_bfloat16* x1hi  = x1lo + SLOT;
    __hip_bfloat16* dslot = (__hip_bfloat16*)d_out;   // (B*128+1)*4 B >= SLOT*2 B

    __hip_bfloat16* WinT  = (__hip_bfloat16*)d_ws;    // 512*512
    __hip_bfloat16* WhT   = WinT + 512 * 512;         // 512*512
    __hip_bfloat16* WoutT = WhT + 512 * 512;          // 128*512
    float* pmin   = (float*)(WoutT + 128 * 512);      // 256*512
    float* pmax   = pmin + 256 * 512;                 // 256*512
    float* cmin   = pmax + 256 * 512;                 // 512
    float* crange = cmin + 512;                       // 512

    // column stats over the full batch (reads x only)
    kminmax<<<256, 512, 0, stream>>>(xf, pmin, pmax, B / 256);
    kbounds<<<1, 512, 0, stream>>>(pmin, pmax, cmin, crange, 256);

    // weight casts (+ transpose to [N,K])
    ktc<<<(512 * 512 + 255) / 256, 256, 0, stream>>>(W_in, WinT, 512);
    ktc<<<(512 * 512 + 255) / 256, 256, 0, stream>>>(W_h, WhT, 512);
    ktc<<<(128 * 512 + 255) / 256, 256, 0, stream>>>(W_out, WoutT, 128);

    // discretize: half0 -> dslot (d_out scratch); half1 -> x0lo (x half0 dead)
    kdisc<<<512, 512, 0, stream>>>(xf, cmin, crange, dslot, HB / 512);
    kdisc<<<512, 512, 0, stream>>>(xf + (size_t)HB * 512, cmin, crange, x0lo, HB / 512);

    kzero<<<1, 64, 0, stream>>>(out + (size_t)B * 128);   // d2_loss = 0

    // GEMM chain, full batch per launch via dual half-pointers.
    // Slot schedule (race-free: read-set disjoint from write-set each launch):
    //   G1 {dslot,x0lo} -> {x0hi,x1lo}
    //   G2..G6 ping-pong {x0hi,x1lo} <-> {x1hi,x0lo}
    //   G7 reads {x1hi,x0lo} -> d_out (dslot dead since G1)
    dim3 gh(4, 1024);   // N=512
    dim3 go(1, 1024);   // N=128
    const int MH = HB / 128;  // 512 tiles per half
    gemm_bias_relu<0><<<gh, 256, 0, stream>>>((const u16*)dslot, (const u16*)x0lo,
        (const u16*)WinT, b_in, x0hi, x1lo, 512, K, MH);
    gemm_bias_relu<0><<<gh, 256, 0, stream>>>((const u16*)x0hi, (const u16*)x1lo,
        (const u16*)WhT, b_h, x1hi, x0lo, 512, K, MH);
    gemm_bias_relu<0><<<gh, 256, 0, stream>>>((const u16*)x1hi, (const u16*)x0lo,
        (const u16*)WhT, b_h, x0hi, x1lo, 512, K, MH);
    gemm_bias_relu<0><<<gh, 256, 0, stream>>>((const u16*)x0hi, (const u16*)x1lo,
        (const u16*)WhT, b_h, x1hi, x0lo, 512, K, MH);
    gemm_bias_relu<0><<<gh, 256, 0, stream>>>((const u16*)x1hi, (const u16*)x0lo,
        (const u16*)WhT, b_h, x0hi, x1lo, 512, K, MH);
    gemm_bias_relu<0><<<gh, 256, 0, stream>>>((const u16*)x0hi, (const u16*)x1lo,
        (const u16*)WhT, b_h, x1hi, x0lo, 512, K, MH);
    gemm_bias_relu<1><<<go, 256, 0, stream>>>((const u16*)x1hi, (const u16*)x0lo,
        (const u16*)WoutT, b_out, out, out + (size_t)HB * 128, 128, K, MH);
}

// Round 3
// 1263.951 us; speedup vs baseline: 1.1770x; 1.1770x over previous
//
#include <hip/hip_runtime.h>
#include <hip/hip_bf16.h>
#include <string.h>

typedef unsigned short u16;
typedef unsigned int u32;
typedef __attribute__((ext_vector_type(8))) short s16x8;   // 8 bf16 (4 VGPRs)
typedef __attribute__((ext_vector_type(4))) float f32x4;

__device__ __forceinline__ u16 bf16bits(float v) {
    union { __hip_bfloat16 b; u16 u; } c;
    c.b = __float2bfloat16(v);
    return c.u;
}

// Reference-exact discretize (validated in round 2):
// idx = #{k in 1..24 : fl(mn + fl(rg*fl(k/25))) < v}. Fast path via u=(v-mn)*s;
// exact fp32 boundary compare only when u is within 1e-3 of an integer.
__device__ __forceinline__ float disc1(float v, float mn, float rg, float s) {
    const float u = __fmul_rn(__fsub_rn(v, mn), s);
    const float rn = rintf(u);
    int idx;
    if (fabsf(u - rn) > 1e-3f) {
        idx = (int)ceilf(u) - 1;
    } else {
        int kc = (int)rn;
        kc = kc < 1 ? 1 : (kc > 24 ? 24 : kc);
        const float cf = __fdiv_rn((float)kc, 25.0f);
        const float b = __fadd_rn(mn, __fmul_rn(rg, cf));
        idx = (int)rn - 1 + ((b < v) ? 1 : 0);
    }
    idx = idx < 0 ? 0 : (idx > 24 ? 24 : idx);
    return (float)idx;
}

// ---------------- per-column min/max, latency-fixed ----------------
// 512 blocks x 512 threads; thread owns a float4 column group; unroll 4
// -> >=16 float4 loads in flight per wave (round-2 version had 1 scalar).
__global__ void kminmax(const float* __restrict__ x, float* __restrict__ pmin,
                        float* __restrict__ pmax) {
    __shared__ float4 smn[512], smx[512];
    const int t = threadIdx.x;
    const int c4 = t & 127;
    const int ro = t >> 7;
    const size_t r0 = (size_t)blockIdx.x * 256;
    float4 mn = {1e30f, 1e30f, 1e30f, 1e30f};
    float4 mx = {-1e30f, -1e30f, -1e30f, -1e30f};
#pragma unroll 4
    for (int i = 0; i < 64; ++i) {
        const int row = ro + i * 4;
        const float4 v = ((const float4*)(x + (r0 + row) * 512))[c4];
        mn.x = fminf(mn.x, v.x); mn.y = fminf(mn.y, v.y);
        mn.z = fminf(mn.z, v.z); mn.w = fminf(mn.w, v.w);
        mx.x = fmaxf(mx.x, v.x); mx.y = fmaxf(mx.y, v.y);
        mx.z = fmaxf(mx.z, v.z); mx.w = fmaxf(mx.w, v.w);
    }
    smn[t] = mn; smx[t] = mx;
    __syncthreads();
    if (t < 128) {
#pragma unroll
        for (int p = 1; p < 4; ++p) {
            const float4 a = smn[t + p * 128], b = smx[t + p * 128];
            mn.x = fminf(mn.x, a.x); mn.y = fminf(mn.y, a.y);
            mn.z = fminf(mn.z, a.z); mn.w = fminf(mn.w, a.w);
            mx.x = fmaxf(mx.x, b.x); mx.y = fmaxf(mx.y, b.y);
            mx.z = fmaxf(mx.z, b.z); mx.w = fmaxf(mx.w, b.w);
        }
        ((float4*)(pmin + blockIdx.x * 512))[c4] = mn;
        ((float4*)(pmax + blockIdx.x * 512))[c4] = mx;
    }
}

__global__ void kred(const float* __restrict__ pmin, const float* __restrict__ pmax,
                     float* __restrict__ p2min, float* __restrict__ p2max, int per) {
    const int c = threadIdx.x;
    const int j = blockIdx.x;
    float mn = 1e30f, mx = -1e30f;
    for (int i = 0; i < per; ++i) {
        mn = fminf(mn, pmin[(size_t)(j * per + i) * 512 + c]);
        mx = fmaxf(mx, pmax[(size_t)(j * per + i) * 512 + c]);
    }
    p2min[j * 512 + c] = mn;
    p2max[j * 512 + c] = mx;
}

__global__ void kbounds(const float* __restrict__ p2min, const float* __restrict__ p2max,
                        float* __restrict__ cmin, float* __restrict__ crange,
                        float* __restrict__ sinv, int np) {
    const int c = threadIdx.x;
    float mn = 1e30f, mx = -1e30f;
    for (int p = 0; p < np; ++p) {
        mn = fminf(mn, p2min[p * 512 + c]);
        mx = fmaxf(mx, p2max[p * 512 + c]);
    }
    cmin[c] = mn;
    const float rg = __fsub_rn(mx, mn);   // matches numpy (b_max-b_min) fp32
    crange[c] = rg;
    sinv[c] = __fdiv_rn(25.0f, rg);
}

// ---------------- W[K,N] fp32 -> Wt[N,K] bf16 ----------------
__global__ void ktc(const float* __restrict__ W, __hip_bfloat16* __restrict__ Wt, int N) {
    const int i = blockIdx.x * 256 + threadIdx.x;
    if (i >= N * 512) return;
    const int n = i >> 9;
    const int k = i & 511;
    Wt[i] = __float2bfloat16(W[(size_t)k * N + n]);
}

__global__ void kzero(float* __restrict__ p) {
    if (threadIdx.x == 0 && blockIdx.x == 0) p[0] = 0.0f;
}

// ---------------- Fused discretize + 7-layer MLP ----------------
// Block = 64 batch rows, 512 threads (8 waves). Activations ping-pong in LDS
// (2 x 64KB, [batch][k] bf16, 16B granule g swizzled to g^(batch&7) -> all LDS
// accesses <=2-way conflicts). Per hidden layer: wave w computes neurons
// w*64..w*64+63 x all 64 batch: D = W(A-op, streamed from L2) . act(B-op, LDS),
// 4x4 tiles of mfma_f32_16x16x32_bf16, 16 K-steps, NO intra-layer barriers.
// C/D layout col=lane&15(batch), row=kq*4+r (4 consecutive neurons) -> 8B
// ds_write_b64 into next act. One barrier per layer.
__global__ __launch_bounds__(512, 2) void megamlp(
    const float* __restrict__ x,
    const float* __restrict__ cmin, const float* __restrict__ crange,
    const float* __restrict__ sinv,
    const u16* __restrict__ WinT, const u16* __restrict__ WhT,
    const u16* __restrict__ WoutT,
    const float* __restrict__ b_in, const float* __restrict__ b_h,
    const float* __restrict__ b_out,
    float* __restrict__ out) {
    __shared__ __attribute__((aligned(16))) u16 act0[64 * 512];   // 64 KB
    __shared__ __attribute__((aligned(16))) u16 act1[64 * 512];   // 64 KB

    const int t = threadIdx.x;
    const int lane = t & 63;
    const int w = t >> 6;          // wave 0..7
    const int lr = lane & 15;
    const int kq = lane >> 4;      // 0..3
    const int xr = lr & 7;
    const size_t row0 = (size_t)blockIdx.x * 64;

    // ---- discretize 64 rows of x into act0 ----
    {
        const int c4 = t & 127;            // float4 column group
        const int ro = t >> 7;             // 0..3
        const float4 mn4 = ((const float4*)cmin)[c4];
        const float4 rg4 = ((const float4*)crange)[c4];
        const float4 s4  = ((const float4*)sinv)[c4];
        const int g16 = c4 >> 1;
        const int hb  = (c4 & 1) << 3;
#pragma unroll 4
        for (int i = 0; i < 16; ++i) {
            const int row = ro + i * 4;
            const float4 v = ((const float4*)(x + (row0 + row) * 512))[c4];
            const u32 lo = (u32)bf16bits(disc1(v.x, mn4.x, rg4.x, s4.x))
                         | ((u32)bf16bits(disc1(v.y, mn4.y, rg4.y, s4.y)) << 16);
            const u32 hi = (u32)bf16bits(disc1(v.z, mn4.z, rg4.z, s4.z))
                         | ((u32)bf16bits(disc1(v.w, mn4.w, rg4.w, s4.w)) << 16);
            const int gg = g16 ^ (row & 7);
            *(uint2*)((char*)act0 + (row << 10) + (gg << 4) + hb) = make_uint2(lo, hi);
        }
    }
    __syncthreads();

    const char* aIn = (const char*)act0;
    char* aOut = (char*)act1;

    // ---- 6 hidden-shaped layers (512 -> 512) ----
    for (int layer = 0; layer < 6; ++layer) {
        const u16* W = (layer == 0) ? WinT : WhT;
        const float* bias = (layer == 0) ? b_in : b_h;

        f32x4 acc[4][4] = {};
        const u16* wp0 = W + ((w * 64 + lr) << 9) + (kq << 3);

#pragma unroll
        for (int ks = 0; ks < 16; ++ks) {
            s16x8 aF[4], bF[4];
#pragma unroll
            for (int mt = 0; mt < 4; ++mt)
                aF[mt] = *(const s16x8*)(wp0 + (mt << 13) + ks * 32);
            const int gg = ((ks << 2) | kq) ^ xr;
#pragma unroll
            for (int nt = 0; nt < 4; ++nt)
                bF[nt] = *(const s16x8*)(aIn + ((nt * 16 + lr) << 10) + (gg << 4));
#pragma unroll
            for (int mt = 0; mt < 4; ++mt)
#pragma unroll
                for (int nt = 0; nt < 4; ++nt)
                    acc[mt][nt] = __builtin_amdgcn_mfma_f32_16x16x32_bf16(
                        aF[mt], bF[nt], acc[mt][nt], 0, 0, 0);
        }

        // epilogue: bias + relu -> bf16 -> aOut[batch][neuron-as-k], swizzled
#pragma unroll
        for (int mt = 0; mt < 4; ++mt) {
            const int g16 = w * 8 + mt * 2 + (kq >> 1);
            float bv[4];
#pragma unroll
            for (int r = 0; r < 4; ++r)
                bv[r] = bias[w * 64 + mt * 16 + kq * 4 + r];
#pragma unroll
            for (int nt = 0; nt < 4; ++nt) {
                const int batch = nt * 16 + lr;
                const float v0 = fmaxf(acc[mt][nt][0] + bv[0], 0.0f);
                const float v1 = fmaxf(acc[mt][nt][1] + bv[1], 0.0f);
                const float v2 = fmaxf(acc[mt][nt][2] + bv[2], 0.0f);
                const float v3 = fmaxf(acc[mt][nt][3] + bv[3], 0.0f);
                const u32 lo = (u32)bf16bits(v0) | ((u32)bf16bits(v1) << 16);
                const u32 hi = (u32)bf16bits(v2) | ((u32)bf16bits(v3) << 16);
                const int gg = g16 ^ (batch & 7);
                *(uint2*)(aOut + (batch << 10) + (gg << 4) + ((kq & 1) << 3)) =
                    make_uint2(lo, hi);
            }
        }
        char* tmp = (char*)aIn; aIn = aOut; aOut = tmp;
        __syncthreads();
    }

    // ---- output layer: 128 neurons; wave w -> neurons w*16..w*16+15 ----
    {
        float* stg = (float*)aOut;    // 64x128 fp32 staging (32 KB of free buffer)
        f32x4 acc[4] = {};
        const u16* wp = WoutT + ((w * 16 + lr) << 9) + (kq << 3);
#pragma unroll
        for (int ks = 0; ks < 16; ++ks) {
            const s16x8 aF = *(const s16x8*)(wp + ks * 32);
            const int gg = ((ks << 2) | kq) ^ xr;
#pragma unroll
            for (int nt = 0; nt < 4; ++nt) {
                const s16x8 bF = *(const s16x8*)(aIn + ((nt * 16 + lr) << 10) + (gg << 4));
                acc[nt] = __builtin_amdgcn_mfma_f32_16x16x32_bf16(aF, bF, acc[nt], 0, 0, 0);
            }
        }
        float bv[4];
#pragma unroll
        for (int r = 0; r < 4; ++r) bv[r] = b_out[w * 16 + kq * 4 + r];
        const int g16o = w * 4 + kq;
#pragma unroll
        for (int nt = 0; nt < 4; ++nt) {
            const int batch = nt * 16 + lr;
            const int gg = g16o ^ (batch & 7);
            float* p = (float*)((char*)stg + (batch << 9) + (gg << 4));
#pragma unroll
            for (int r = 0; r < 4; ++r)
                p[r] = fmaxf(acc[nt][r] + bv[r], 0.0f);
        }
    }
    __syncthreads();

    // ---- coalesced dump of staged [64][128] fp32 ----
    {
        const float* stg = (const float*)aOut;
        const int n4 = t & 31;
        const int bo = t >> 5;          // 0..15
#pragma unroll
        for (int pp = 0; pp < 4; ++pp) {
            const int batch = pp * 16 + bo;
            const int gg = n4 ^ (batch & 7);
            const float4 v = *(const float4*)((const char*)stg + (batch << 9) + (gg << 4));
            ((float4*)(out + (row0 + batch) * 128))[n4] = v;
        }
    }
}

extern "C" void kernel_launch(void* const* d_in, const int* in_sizes, int n_in,
                              void* d_out, int out_size, void* d_ws, size_t ws_size,
                              hipStream_t stream) {
    const float* x     = (const float*)d_in[0];
    const float* W_in  = (const float*)d_in[1];
    const float* b_in  = (const float*)d_in[2];
    const float* W_h   = (const float*)d_in[3];
    const float* b_h   = (const float*)d_in[4];
    const float* W_out = (const float*)d_in[5];
    const float* b_out = (const float*)d_in[6];
    float* out = (float*)d_out;

    const int B = in_sizes[0] / 512;       // 131072
    const int NP1 = B / 256;               // 512 minmax partial blocks

    // workspace (~3.2 MB)
    __hip_bfloat16* WinT  = (__hip_bfloat16*)d_ws;           // 512*512
    __hip_bfloat16* WhT   = WinT + 512 * 512;                // 512*512
    __hip_bfloat16* WoutT = WhT + 512 * 512;                 // 128*512
    float* pmin   = (float*)(WoutT + 128 * 512);             // NP1*512
    float* pmax   = pmin + (size_t)NP1 * 512;                // NP1*512
    float* p2min  = pmax + (size_t)NP1 * 512;                // 8*512
    float* p2max  = p2min + 8 * 512;                         // 8*512
    float* cmin   = p2max + 8 * 512;                         // 512
    float* crange = cmin + 512;                              // 512
    float* sinv   = crange + 512;                            // 512

    kminmax<<<NP1, 512, 0, stream>>>(x, pmin, pmax);
    kred<<<8, 512, 0, stream>>>(pmin, pmax, p2min, p2max, NP1 / 8);
    kbounds<<<1, 512, 0, stream>>>(p2min, p2max, cmin, crange, sinv, 8);

    ktc<<<(512 * 512 + 255) / 256, 256, 0, stream>>>(W_in, WinT, 512);
    ktc<<<(512 * 512 + 255) / 256, 256, 0, stream>>>(W_h, WhT, 512);
    ktc<<<(128 * 512 + 255) / 256, 256, 0, stream>>>(W_out, WoutT, 128);
    kzero<<<1, 64, 0, stream>>>(out + (size_t)B * 128);      // d2_loss = 0

    megamlp<<<B / 64, 512, 0, stream>>>(x, cmin, crange, sinv,
        (const u16*)WinT, (const u16*)WhT, (const u16*)WoutT,
        b_in, b_h, b_out, out);
}

// Round 4
// 1254.224 us; speedup vs baseline: 1.1862x; 1.0078x over previous
//
#include <hip/hip_runtime.h>
#include <hip/hip_bf16.h>

typedef unsigned short u16;
typedef unsigned int u32;
typedef __attribute__((ext_vector_type(8))) short s16x8;   // 8 bf16 (4 VGPRs)
typedef __attribute__((ext_vector_type(4))) float f32x4;

__device__ __forceinline__ u16 bf16bits(float v) {
    union { __hip_bfloat16 b; u16 u; } c;
    c.b = __float2bfloat16(v);
    return c.u;
}

// Reference-exact discretize (validated rounds 2-3):
// idx = #{k in 1..24 : fl(mn + fl(rg*fl(k/25))) < v}. Fast path via u=(v-mn)*s;
// exact fp32 boundary compare only when u is within 1e-3 of an integer.
__device__ __forceinline__ float disc1(float v, float mn, float rg, float s) {
    const float u = __fmul_rn(__fsub_rn(v, mn), s);
    const float rn = rintf(u);
    int idx;
    if (fabsf(u - rn) > 1e-3f) {
        idx = (int)ceilf(u) - 1;
    } else {
        int kc = (int)rn;
        kc = kc < 1 ? 1 : (kc > 24 ? 24 : kc);
        const float cf = __fdiv_rn((float)kc, 25.0f);
        const float b = __fadd_rn(mn, __fmul_rn(rg, cf));
        idx = (int)rn - 1 + ((b < v) ? 1 : 0);
    }
    idx = idx < 0 ? 0 : (idx > 24 ? 24 : idx);
    return (float)idx;
}

// ---------------- per-column min/max ----------------
__global__ void kminmax(const float* __restrict__ x, float* __restrict__ pmin,
                        float* __restrict__ pmax) {
    __shared__ float4 smn[512], smx[512];
    const int t = threadIdx.x;
    const int c4 = t & 127;
    const int ro = t >> 7;
    const size_t r0 = (size_t)blockIdx.x * 256;
    float4 mn = {1e30f, 1e30f, 1e30f, 1e30f};
    float4 mx = {-1e30f, -1e30f, -1e30f, -1e30f};
#pragma unroll 8
    for (int i = 0; i < 64; ++i) {
        const int row = ro + i * 4;
        const float4 v = ((const float4*)(x + (r0 + row) * 512))[c4];
        mn.x = fminf(mn.x, v.x); mn.y = fminf(mn.y, v.y);
        mn.z = fminf(mn.z, v.z); mn.w = fminf(mn.w, v.w);
        mx.x = fmaxf(mx.x, v.x); mx.y = fmaxf(mx.y, v.y);
        mx.z = fmaxf(mx.z, v.z); mx.w = fmaxf(mx.w, v.w);
    }
    smn[t] = mn; smx[t] = mx;
    __syncthreads();
    if (t < 128) {
#pragma unroll
        for (int p = 1; p < 4; ++p) {
            const float4 a = smn[t + p * 128], b = smx[t + p * 128];
            mn.x = fminf(mn.x, a.x); mn.y = fminf(mn.y, a.y);
            mn.z = fminf(mn.z, a.z); mn.w = fminf(mn.w, a.w);
            mx.x = fmaxf(mx.x, b.x); mx.y = fmaxf(mx.y, b.y);
            mx.z = fmaxf(mx.z, b.z); mx.w = fmaxf(mx.w, b.w);
        }
        ((float4*)(pmin + blockIdx.x * 512))[c4] = mn;
        ((float4*)(pmax + blockIdx.x * 512))[c4] = mx;
    }
}

__global__ void kred(const float* __restrict__ pmin, const float* __restrict__ pmax,
                     float* __restrict__ p2min, float* __restrict__ p2max, int per) {
    const int c = threadIdx.x;
    const int j = blockIdx.x;
    float mn = 1e30f, mx = -1e30f;
    for (int i = 0; i < per; ++i) {
        mn = fminf(mn, pmin[(size_t)(j * per + i) * 512 + c]);
        mx = fmaxf(mx, pmax[(size_t)(j * per + i) * 512 + c]);
    }
    p2min[j * 512 + c] = mn;
    p2max[j * 512 + c] = mx;
}

__global__ void kbounds(const float* __restrict__ p2min, const float* __restrict__ p2max,
                        float* __restrict__ cmin, float* __restrict__ crange,
                        float* __restrict__ sinv, int np, float* __restrict__ dloss) {
    const int c = threadIdx.x;
    float mn = 1e30f, mx = -1e30f;
    for (int p = 0; p < np; ++p) {
        mn = fminf(mn, p2min[p * 512 + c]);
        mx = fmaxf(mx, p2max[p * 512 + c]);
    }
    cmin[c] = mn;
    const float rg = __fsub_rn(mx, mn);   // matches numpy (b_max-b_min) fp32
    crange[c] = rg;
    sinv[c] = __fdiv_rn(25.0f, rg);
    if (c == 0) dloss[0] = 0.0f;          // d2_loss
}

// ---------------- all three weight casts W[K,N] fp32 -> Wt[N,K] bf16 ----------------
__global__ void ktc_all(const float* __restrict__ W_in, const float* __restrict__ W_h,
                        const float* __restrict__ W_out,
                        __hip_bfloat16* __restrict__ WinT, __hip_bfloat16* __restrict__ WhT,
                        __hip_bfloat16* __restrict__ WoutT) {
    const int i = blockIdx.x * 256 + threadIdx.x;
    if (i < 512 * 512) {
        WinT[i] = __float2bfloat16(W_in[(size_t)(i & 511) * 512 + (i >> 9)]);
    } else if (i < 2 * 512 * 512) {
        const int j = i - 512 * 512;
        WhT[j] = __float2bfloat16(W_h[(size_t)(j & 511) * 512 + (j >> 9)]);
    } else if (i < 2 * 512 * 512 + 128 * 512) {
        const int j = i - 2 * 512 * 512;
        WoutT[j] = __float2bfloat16(W_out[(size_t)(j & 511) * 128 + (j >> 9)]);
    }
}

// ---------------- Fused discretize + 7-layer MLP ----------------
// Block = 64 batch rows, 512 threads (8 waves). Activations ping-pong in LDS
// (2 x 64KB, [batch][k] bf16, 16B granule g swizzled to g^(batch&7)). Wave w
// computes neurons w*64..w*64+63 x all 64 batch: D = W(A-op, global/L2) .
// act(B-op, LDS), 4x4 mfma_f32_16x16x32_bf16, 16 K-steps, no intra-layer
// barriers, one barrier per layer. Round-4 change: depth-2 software pipeline
// on BOTH the weight (global) and act (LDS) fragments so consumers wait at
// vmcnt(~8)/lgkmcnt(~4) instead of exposing full L2 latency per K-step.
__global__ __launch_bounds__(512, 2) void megamlp(
    const float* __restrict__ x,
    const float* __restrict__ cmin, const float* __restrict__ crange,
    const float* __restrict__ sinv,
    const u16* __restrict__ WinT, const u16* __restrict__ WhT,
    const u16* __restrict__ WoutT,
    const float* __restrict__ b_in, const float* __restrict__ b_h,
    const float* __restrict__ b_out,
    float* __restrict__ out) {
    __shared__ __attribute__((aligned(16))) u16 act0[64 * 512];   // 64 KB
    __shared__ __attribute__((aligned(16))) u16 act1[64 * 512];   // 64 KB

    const int t = threadIdx.x;
    const int lane = t & 63;
    const int w = t >> 6;          // wave 0..7
    const int lr = lane & 15;
    const int kq = lane >> 4;      // 0..3
    const int xr = lr & 7;
    const size_t row0 = (size_t)blockIdx.x * 64;

    // ---- discretize 64 rows of x into act0 ----
    {
        const int c4 = t & 127;            // float4 column group
        const int ro = t >> 7;             // 0..3
        const float4 mn4 = ((const float4*)cmin)[c4];
        const float4 rg4 = ((const float4*)crange)[c4];
        const float4 s4  = ((const float4*)sinv)[c4];
        const int g16 = c4 >> 1;
        const int hb  = (c4 & 1) << 3;
#pragma unroll 8
        for (int i = 0; i < 16; ++i) {
            const int row = ro + i * 4;
            const float4 v = ((const float4*)(x + (row0 + row) * 512))[c4];
            const u32 lo = (u32)bf16bits(disc1(v.x, mn4.x, rg4.x, s4.x))
                         | ((u32)bf16bits(disc1(v.y, mn4.y, rg4.y, s4.y)) << 16);
            const u32 hi = (u32)bf16bits(disc1(v.z, mn4.z, rg4.z, s4.z))
                         | ((u32)bf16bits(disc1(v.w, mn4.w, rg4.w, s4.w)) << 16);
            const int gg = g16 ^ (row & 7);
            *(uint2*)((char*)act0 + (row << 10) + (gg << 4) + hb) = make_uint2(lo, hi);
        }
    }
    __syncthreads();

    const char* aIn = (const char*)act0;
    char* aOut = (char*)act1;

    // ---- 6 hidden-shaped layers (512 -> 512) ----
    for (int layer = 0; layer < 6; ++layer) {
        const u16* W = (layer == 0) ? WinT : WhT;
        const float* bias = (layer == 0) ? b_in : b_h;

        f32x4 acc[4][4] = {};
        const u16* wp0 = W + ((w * 64 + lr) << 9) + (kq << 3);

        s16x8 aF[3][4], bF[3][4];
        auto loadA = [&](int ks, int slot) {
#pragma unroll
            for (int mt = 0; mt < 4; ++mt)
                aF[slot][mt] = *(const s16x8*)(wp0 + (mt << 13) + ks * 32);
        };
        auto loadB = [&](int ks, int slot) {
            const int gg = ((ks << 2) | kq) ^ xr;
#pragma unroll
            for (int nt = 0; nt < 4; ++nt)
                bF[slot][nt] = *(const s16x8*)(aIn + ((nt * 16 + lr) << 10) + (gg << 4));
        };

        loadA(0, 0); loadB(0, 0);
        loadA(1, 1); loadB(1, 1);
#pragma unroll
        for (int ks = 0; ks < 16; ++ks) {
            const int cur = ks % 3;
            if (ks + 2 < 16) {
                const int nx = (ks + 2) % 3;
                loadA(ks + 2, nx);
                loadB(ks + 2, nx);
            }
#pragma unroll
            for (int mt = 0; mt < 4; ++mt)
#pragma unroll
                for (int nt = 0; nt < 4; ++nt)
                    acc[mt][nt] = __builtin_amdgcn_mfma_f32_16x16x32_bf16(
                        aF[cur][mt], bF[cur][nt], acc[mt][nt], 0, 0, 0);
        }

        // epilogue: bias + relu -> bf16 -> aOut[batch][neuron-as-k], swizzled
#pragma unroll
        for (int mt = 0; mt < 4; ++mt) {
            const int g16 = w * 8 + mt * 2 + (kq >> 1);
            float bv[4];
#pragma unroll
            for (int r = 0; r < 4; ++r)
                bv[r] = bias[w * 64 + mt * 16 + kq * 4 + r];
#pragma unroll
            for (int nt = 0; nt < 4; ++nt) {
                const int batch = nt * 16 + lr;
                const float v0 = fmaxf(acc[mt][nt][0] + bv[0], 0.0f);
                const float v1 = fmaxf(acc[mt][nt][1] + bv[1], 0.0f);
                const float v2 = fmaxf(acc[mt][nt][2] + bv[2], 0.0f);
                const float v3 = fmaxf(acc[mt][nt][3] + bv[3], 0.0f);
                const u32 lo = (u32)bf16bits(v0) | ((u32)bf16bits(v1) << 16);
                const u32 hi = (u32)bf16bits(v2) | ((u32)bf16bits(v3) << 16);
                const int gg = g16 ^ (batch & 7);
                *(uint2*)(aOut + (batch << 10) + (gg << 4) + ((kq & 1) << 3)) =
                    make_uint2(lo, hi);
            }
        }
        char* tmp = (char*)aIn; aIn = aOut; aOut = tmp;
        __syncthreads();
    }

    // ---- output layer: 128 neurons; wave w -> neurons w*16..w*16+15 ----
    {
        float* stg = (float*)aOut;    // 64x128 fp32 staging in the free buffer
        f32x4 acc[4] = {};
        const u16* wp = WoutT + ((w * 16 + lr) << 9) + (kq << 3);

        s16x8 aF[3], bF[3][4];
        auto loadA1 = [&](int ks, int slot) {
            aF[slot] = *(const s16x8*)(wp + ks * 32);
        };
        auto loadB1 = [&](int ks, int slot) {
            const int gg = ((ks << 2) | kq) ^ xr;
#pragma unroll
            for (int nt = 0; nt < 4; ++nt)
                bF[slot][nt] = *(const s16x8*)(aIn + ((nt * 16 + lr) << 10) + (gg << 4));
        };
        loadA1(0, 0); loadB1(0, 0);
        loadA1(1, 1); loadB1(1, 1);
#pragma unroll
        for (int ks = 0; ks < 16; ++ks) {
            const int cur = ks % 3;
            if (ks + 2 < 16) {
                const int nx = (ks + 2) % 3;
                loadA1(ks + 2, nx);
                loadB1(ks + 2, nx);
            }
#pragma unroll
            for (int nt = 0; nt < 4; ++nt)
                acc[nt] = __builtin_amdgcn_mfma_f32_16x16x32_bf16(
                    aF[cur], bF[cur][nt], acc[nt], 0, 0, 0);
        }
        float bv[4];
#pragma unroll
        for (int r = 0; r < 4; ++r) bv[r] = b_out[w * 16 + kq * 4 + r];
        const int g16o = w * 4 + kq;
#pragma unroll
        for (int nt = 0; nt < 4; ++nt) {
            const int batch = nt * 16 + lr;
            const int gg = g16o ^ (batch & 7);
            float* p = (float*)((char*)stg + (batch << 9) + (gg << 4));
#pragma unroll
            for (int r = 0; r < 4; ++r)
                p[r] = fmaxf(acc[nt][r] + bv[r], 0.0f);
        }
    }
    __syncthreads();

    // ---- coalesced dump of staged [64][128] fp32 ----
    {
        const float* stg = (const float*)aOut;
        const int n4 = t & 31;
        const int bo = t >> 5;          // 0..15
#pragma unroll
        for (int pp = 0; pp < 4; ++pp) {
            const int batch = pp * 16 + bo;
            const int gg = n4 ^ (batch & 7);
            const float4 v = *(const float4*)((const char*)stg + (batch << 9) + (gg << 4));
            ((float4*)(out + (row0 + batch) * 128))[n4] = v;
        }
    }
}

extern "C" void kernel_launch(void* const* d_in, const int* in_sizes, int n_in,
                              void* d_out, int out_size, void* d_ws, size_t ws_size,
                              hipStream_t stream) {
    const float* x     = (const float*)d_in[0];
    const float* W_in  = (const float*)d_in[1];
    const float* b_in  = (const float*)d_in[2];
    const float* W_h   = (const float*)d_in[3];
    const float* b_h   = (const float*)d_in[4];
    const float* W_out = (const float*)d_in[5];
    const float* b_out = (const float*)d_in[6];
    float* out = (float*)d_out;

    const int B = in_sizes[0] / 512;       // 131072
    const int NP1 = B / 256;               // 512 minmax partial blocks

    // workspace (~3.2 MB)
    __hip_bfloat16* WinT  = (__hip_bfloat16*)d_ws;           // 512*512
    __hip_bfloat16* WhT   = WinT + 512 * 512;                // 512*512
    __hip_bfloat16* WoutT = WhT + 512 * 512;                 // 128*512
    float* pmin   = (float*)(WoutT + 128 * 512);             // NP1*512
    float* pmax   = pmin + (size_t)NP1 * 512;                // NP1*512
    float* p2min  = pmax + (size_t)NP1 * 512;                // 8*512
    float* p2max  = p2min + 8 * 512;                         // 8*512
    float* cmin   = p2max + 8 * 512;                         // 512
    float* crange = cmin + 512;                              // 512
    float* sinv   = crange + 512;                            // 512

    kminmax<<<NP1, 512, 0, stream>>>(x, pmin, pmax);
    kred<<<8, 512, 0, stream>>>(pmin, pmax, p2min, p2max, NP1 / 8);
    kbounds<<<1, 512, 0, stream>>>(p2min, p2max, cmin, crange, sinv, 8,
                                   out + (size_t)B * 128);
    ktc_all<<<(2 * 512 * 512 + 128 * 512 + 255) / 256, 256, 0, stream>>>(
        W_in, W_h, W_out, WinT, WhT, WoutT);

    megamlp<<<B / 64, 512, 0, stream>>>(x, cmin, crange, sinv,
        (const u16*)WinT, (const u16*)WhT, (const u16*)WoutT,
        b_in, b_h, b_out, out);
}

// Round 5
// 960.253 us; speedup vs baseline: 1.5493x; 1.3061x over previous
//
#include <hip/hip_runtime.h>
#include <hip/hip_bf16.h>

typedef unsigned short u16;
typedef unsigned int u32;
typedef __attribute__((ext_vector_type(8))) short s16x8;   // 8 bf16 (4 VGPRs)
typedef __attribute__((ext_vector_type(4))) float f32x4;

__device__ __forceinline__ u16 bf16bits(float v) {
    union { __hip_bfloat16 b; u16 u; } c;
    c.b = __float2bfloat16(v);
    return c.u;
}

// Reference-exact discretize (validated rounds 2-4).
__device__ __forceinline__ float disc1(float v, float mn, float rg, float s) {
    const float u = __fmul_rn(__fsub_rn(v, mn), s);
    const float rn = rintf(u);
    int idx;
    if (fabsf(u - rn) > 1e-3f) {
        idx = (int)ceilf(u) - 1;
    } else {
        int kc = (int)rn;
        kc = kc < 1 ? 1 : (kc > 24 ? 24 : kc);
        const float cf = __fdiv_rn((float)kc, 25.0f);
        const float b = __fadd_rn(mn, __fmul_rn(rg, cf));
        idx = (int)rn - 1 + ((b < v) ? 1 : 0);
    }
    idx = idx < 0 ? 0 : (idx > 24 ? 24 : idx);
    return (float)idx;
}

// ---------------- per-column min/max: 1024 blocks x 128 rows ----------------
__global__ void kminmax(const float* __restrict__ x, float* __restrict__ pmin,
                        float* __restrict__ pmax) {
    __shared__ float4 smn[512], smx[512];
    const int t = threadIdx.x;
    const int c4 = t & 127;
    const int ro = t >> 7;
    const size_t r0 = (size_t)blockIdx.x * 128;
    float4 mn = {1e30f, 1e30f, 1e30f, 1e30f};
    float4 mx = {-1e30f, -1e30f, -1e30f, -1e30f};
#pragma unroll 8
    for (int i = 0; i < 32; ++i) {
        const int row = ro + i * 4;
        const float4 v = ((const float4*)(x + (r0 + row) * 512))[c4];
        mn.x = fminf(mn.x, v.x); mn.y = fminf(mn.y, v.y);
        mn.z = fminf(mn.z, v.z); mn.w = fminf(mn.w, v.w);
        mx.x = fmaxf(mx.x, v.x); mx.y = fmaxf(mx.y, v.y);
        mx.z = fmaxf(mx.z, v.z); mx.w = fmaxf(mx.w, v.w);
    }
    smn[t] = mn; smx[t] = mx;
    __syncthreads();
    if (t < 128) {
#pragma unroll
        for (int p = 1; p < 4; ++p) {
            const float4 a = smn[t + p * 128], b = smx[t + p * 128];
            mn.x = fminf(mn.x, a.x); mn.y = fminf(mn.y, a.y);
            mn.z = fminf(mn.z, a.z); mn.w = fminf(mn.w, a.w);
            mx.x = fmaxf(mx.x, b.x); mx.y = fmaxf(mx.y, b.y);
            mx.z = fmaxf(mx.z, b.z); mx.w = fmaxf(mx.w, b.w);
        }
        ((float4*)(pmin + blockIdx.x * 512))[c4] = mn;
        ((float4*)(pmax + blockIdx.x * 512))[c4] = mx;
    }
}

__global__ void kred(const float* __restrict__ pmin, const float* __restrict__ pmax,
                     float* __restrict__ p2min, float* __restrict__ p2max, int per) {
    const int c = threadIdx.x;
    const int j = blockIdx.x;
    float mn = 1e30f, mx = -1e30f;
    for (int i = 0; i < per; ++i) {
        mn = fminf(mn, pmin[(size_t)(j * per + i) * 512 + c]);
        mx = fmaxf(mx, pmax[(size_t)(j * per + i) * 512 + c]);
    }
    p2min[j * 512 + c] = mn;
    p2max[j * 512 + c] = mx;
}

__global__ void kbounds(const float* __restrict__ p2min, const float* __restrict__ p2max,
                        float* __restrict__ cmin, float* __restrict__ crange,
                        float* __restrict__ sinv, int np, float* __restrict__ dloss) {
    const int c = threadIdx.x;
    float mn = 1e30f, mx = -1e30f;
    for (int p = 0; p < np; ++p) {
        mn = fminf(mn, p2min[p * 512 + c]);
        mx = fmaxf(mx, p2max[p * 512 + c]);
    }
    cmin[c] = mn;
    const float rg = __fsub_rn(mx, mn);
    crange[c] = rg;
    sinv[c] = __fdiv_rn(25.0f, rg);
    if (c == 0) dloss[0] = 0.0f;          // d2_loss
}

// ---------------- weight casts W[K,N] fp32 -> Wt[N,K] bf16 ----------------
__global__ void ktc_all(const float* __restrict__ W_in, const float* __restrict__ W_h,
                        const float* __restrict__ W_out,
                        __hip_bfloat16* __restrict__ WinT, __hip_bfloat16* __restrict__ WhT,
                        __hip_bfloat16* __restrict__ WoutT) {
    const int i = blockIdx.x * 256 + threadIdx.x;
    if (i < 512 * 512) {
        WinT[i] = __float2bfloat16(W_in[(size_t)(i & 511) * 512 + (i >> 9)]);
    } else if (i < 2 * 512 * 512) {
        const int j = i - 512 * 512;
        WhT[j] = __float2bfloat16(W_h[(size_t)(j & 511) * 512 + (j >> 9)]);
    } else if (i < 2 * 512 * 512 + 128 * 512) {
        const int j = i - 2 * 512 * 512;
        WoutT[j] = __float2bfloat16(W_out[(size_t)(j & 511) * 128 + (j >> 9)]);
    }
}

// ---------------- Fused discretize + 7-layer MLP, 128 rows/block ----------------
// Block = 128 batch rows (two 64-row LDS act buffers, IN-PLACE layer update:
// phase A reads everything into acc, barrier, phase B overwrites, barrier).
// Wave w computes neurons w*64..w*64+63 for ALL 128 batch rows: per K-step
// 4 weight frags (global/L2) feed 32 MFMAs -> 1024 SIMD-cyc of MFMA per
// ~225-cyc L2 latency, latency-robust even at 2 waves/SIMD lockstep.
// Act layout per 64-row buffer: [row][k] bf16, 16B granule g at g^(row&7).
__global__ __launch_bounds__(512, 2) void megamlp(
    const float* __restrict__ x,
    const float* __restrict__ cmin, const float* __restrict__ crange,
    const float* __restrict__ sinv,
    const u16* __restrict__ WinT, const u16* __restrict__ WhT,
    const u16* __restrict__ WoutT,
    const float* __restrict__ b_in, const float* __restrict__ b_h,
    const float* __restrict__ b_out,
    float* __restrict__ out) {
    __shared__ __attribute__((aligned(16))) u16 actA[64 * 512];   // 64 KB
    __shared__ __attribute__((aligned(16))) u16 actB[64 * 512];   // 64 KB

    const int t = threadIdx.x;
    const int lane = t & 63;
    const int w = t >> 6;          // wave 0..7
    const int lr = lane & 15;
    const int kq = lane >> 4;      // 0..3
    const int xr = lr & 7;
    const size_t row0 = (size_t)blockIdx.x * 128;

    // ---- discretize 128 rows of x into actA (rows 0-63) / actB (64-127) ----
    {
        const int c4 = t & 127;
        const int ro = t >> 7;             // 0..3
        const float4 mn4 = ((const float4*)cmin)[c4];
        const float4 rg4 = ((const float4*)crange)[c4];
        const float4 s4  = ((const float4*)sinv)[c4];
        const int g16 = c4 >> 1;
        const int hb  = (c4 & 1) << 3;
#pragma unroll 8
        for (int i = 0; i < 32; ++i) {
            const int row = ro + i * 4;          // 0..127
            const float4 v = ((const float4*)(x + (row0 + row) * 512))[c4];
            const u32 lo = (u32)bf16bits(disc1(v.x, mn4.x, rg4.x, s4.x))
                         | ((u32)bf16bits(disc1(v.y, mn4.y, rg4.y, s4.y)) << 16);
            const u32 hi = (u32)bf16bits(disc1(v.z, mn4.z, rg4.z, s4.z))
                         | ((u32)bf16bits(disc1(v.w, mn4.w, rg4.w, s4.w)) << 16);
            const int rl = row & 63;
            const int gg = g16 ^ (rl & 7);
            char* base = (row < 64) ? (char*)actA : (char*)actB;
            *(uint2*)(base + (rl << 10) + (gg << 4) + hb) = make_uint2(lo, hi);
        }
    }
    __syncthreads();

    // ---- 6 hidden-shaped layers (512 -> 512), in-place ----
    for (int layer = 0; layer < 6; ++layer) {
        const u16* W = (layer == 0) ? WinT : WhT;
        const float* bias = (layer == 0) ? b_in : b_h;

        f32x4 acc[2][4][4] = {};
        const u16* wp0 = W + ((w * 64 + lr) << 9) + (kq << 3);

        s16x8 aF[4], aN[4];
#pragma unroll
        for (int mt = 0; mt < 4; ++mt)
            aF[mt] = *(const s16x8*)(wp0 + (mt << 13));

#pragma unroll
        for (int ks = 0; ks < 16; ++ks) {
            if (ks < 15) {
                const u16* wn = wp0 + (ks + 1) * 32;
#pragma unroll
                for (int mt = 0; mt < 4; ++mt)
                    aN[mt] = *(const s16x8*)(wn + (mt << 13));
            }
            const int gg = ((ks << 2) | kq) ^ xr;
#pragma unroll
            for (int h = 0; h < 2; ++h) {
                const char* ah = h ? (const char*)actB : (const char*)actA;
                s16x8 bF[4];
#pragma unroll
                for (int nt = 0; nt < 4; ++nt)
                    bF[nt] = *(const s16x8*)(ah + ((nt * 16 + lr) << 10) + (gg << 4));
#pragma unroll
                for (int mt = 0; mt < 4; ++mt)
#pragma unroll
                    for (int nt = 0; nt < 4; ++nt)
                        acc[h][mt][nt] = __builtin_amdgcn_mfma_f32_16x16x32_bf16(
                            aF[mt], bF[nt], acc[h][mt][nt], 0, 0, 0);
            }
#pragma unroll
            for (int mt = 0; mt < 4; ++mt) aF[mt] = aN[mt];
        }
        __syncthreads();   // all reads done -> safe to overwrite in place

        // phase B: bias + relu -> bf16 -> act[batch][neuron-as-k], swizzled
#pragma unroll
        for (int mt = 0; mt < 4; ++mt) {
            const int g16 = w * 8 + mt * 2 + (kq >> 1);
            float bv[4];
#pragma unroll
            for (int r = 0; r < 4; ++r)
                bv[r] = bias[w * 64 + mt * 16 + kq * 4 + r];
#pragma unroll
            for (int h = 0; h < 2; ++h) {
                char* ah = h ? (char*)actB : (char*)actA;
#pragma unroll
                for (int nt = 0; nt < 4; ++nt) {
                    const int batch = nt * 16 + lr;
                    const float v0 = fmaxf(acc[h][mt][nt][0] + bv[0], 0.0f);
                    const float v1 = fmaxf(acc[h][mt][nt][1] + bv[1], 0.0f);
                    const float v2 = fmaxf(acc[h][mt][nt][2] + bv[2], 0.0f);
                    const float v3 = fmaxf(acc[h][mt][nt][3] + bv[3], 0.0f);
                    const u32 lo = (u32)bf16bits(v0) | ((u32)bf16bits(v1) << 16);
                    const u32 hi = (u32)bf16bits(v2) | ((u32)bf16bits(v3) << 16);
                    const int gg = g16 ^ (batch & 7);
                    *(uint2*)(ah + (batch << 10) + (gg << 4) + ((kq & 1) << 3)) =
                        make_uint2(lo, hi);
                }
            }
        }
        __syncthreads();
    }

    // ---- output layer: 128 neurons; wave w -> neurons w*16..w*16+15 ----
    {
        f32x4 acc[2][4] = {};
        const u16* wp = WoutT + ((w * 16 + lr) << 9) + (kq << 3);
        s16x8 aF = *(const s16x8*)(wp);
#pragma unroll
        for (int ks = 0; ks < 16; ++ks) {
            s16x8 aN;
            if (ks < 15) aN = *(const s16x8*)(wp + (ks + 1) * 32);
            const int gg = ((ks << 2) | kq) ^ xr;
#pragma unroll
            for (int h = 0; h < 2; ++h) {
                const char* ah = h ? (const char*)actB : (const char*)actA;
#pragma unroll
                for (int nt = 0; nt < 4; ++nt) {
                    const s16x8 bF = *(const s16x8*)(ah + ((nt * 16 + lr) << 10) + (gg << 4));
                    acc[h][nt] = __builtin_amdgcn_mfma_f32_16x16x32_bf16(
                        aF, bF, acc[h][nt], 0, 0, 0);
                }
            }
            aF = aN;
        }
        __syncthreads();   // reads done; stage fp32 [64][128] per half in place

        float bv[4];
#pragma unroll
        for (int r = 0; r < 4; ++r) bv[r] = b_out[w * 16 + kq * 4 + r];
        const int g16o = w * 4 + kq;
#pragma unroll
        for (int h = 0; h < 2; ++h) {
            char* sh = h ? (char*)actB : (char*)actA;
#pragma unroll
            for (int nt = 0; nt < 4; ++nt) {
                const int batch = nt * 16 + lr;
                const int gg = g16o ^ (batch & 7);
                float* p = (float*)(sh + (batch << 9) + (gg << 4));
#pragma unroll
                for (int r = 0; r < 4; ++r)
                    p[r] = fmaxf(acc[h][nt][r] + bv[r], 0.0f);
            }
        }
    }
    __syncthreads();

    // ---- coalesced dump of staged 2x[64][128] fp32 ----
    {
        const int n4 = t & 31;
        const int bo = t >> 5;          // 0..15
#pragma unroll
        for (int h = 0; h < 2; ++h) {
            const char* sh = h ? (const char*)actB : (const char*)actA;
#pragma unroll
            for (int pp = 0; pp < 4; ++pp) {
                const int batch = pp * 16 + bo;
                const int gg = n4 ^ (batch & 7);
                const float4 v = *(const float4*)(sh + (batch << 9) + (gg << 4));
                ((float4*)(out + (row0 + h * 64 + batch) * 128))[n4] = v;
            }
        }
    }
}

extern "C" void kernel_launch(void* const* d_in, const int* in_sizes, int n_in,
                              void* d_out, int out_size, void* d_ws, size_t ws_size,
                              hipStream_t stream) {
    const float* x     = (const float*)d_in[0];
    const float* W_in  = (const float*)d_in[1];
    const float* b_in  = (const float*)d_in[2];
    const float* W_h   = (const float*)d_in[3];
    const float* b_h   = (const float*)d_in[4];
    const float* W_out = (const float*)d_in[5];
    const float* b_out = (const float*)d_in[6];
    float* out = (float*)d_out;

    const int B = in_sizes[0] / 512;       // 131072
    const int NP1 = B / 128;               // 1024 minmax partial blocks

    // workspace (~5.5 MB)
    __hip_bfloat16* WinT  = (__hip_bfloat16*)d_ws;           // 512*512
    __hip_bfloat16* WhT   = WinT + 512 * 512;                // 512*512
    __hip_bfloat16* WoutT = WhT + 512 * 512;                 // 128*512
    float* pmin   = (float*)(WoutT + 128 * 512);             // NP1*512
    float* pmax   = pmin + (size_t)NP1 * 512;                // NP1*512
    float* p2min  = pmax + (size_t)NP1 * 512;                // 64*512
    float* p2max  = p2min + 64 * 512;                        // 64*512
    float* cmin   = p2max + 64 * 512;                        // 512
    float* crange = cmin + 512;                              // 512
    float* sinv   = crange + 512;                            // 512

    kminmax<<<NP1, 512, 0, stream>>>(x, pmin, pmax);
    kred<<<64, 512, 0, stream>>>(pmin, pmax, p2min, p2max, NP1 / 64);
    kbounds<<<1, 512, 0, stream>>>(p2min, p2max, cmin, crange, sinv, 64,
                                   out + (size_t)B * 128);
    ktc_all<<<(2 * 512 * 512 + 128 * 512 + 255) / 256, 256, 0, stream>>>(
        W_in, W_h, W_out, WinT, WhT, WoutT);

    megamlp<<<B / 128, 512, 0, stream>>>(x, cmin, crange, sinv,
        (const u16*)WinT, (const u16*)WhT, (const u16*)WoutT,
        b_in, b_h, b_out, out);
}